// Round 13
// baseline (304.841 us; speedup 1.0000x reference)
//
#include <hip/hip_runtime.h>
#include <hip/hip_bf16.h>
#include <math.h>

#define B_    500
#define T_    100
#define I_    700
#define HALF_ 350
#define H_    512
#define O_    20
#define M_    (B_*T_)     // 50000
#define BH_   (B_*H_)     // 256000
#define TP_   112         // T padded to 7*16
#define KP_   352         // padded K per phase
#define ASTR_ 40          // A LDS row stride shorts (80B)
#define ABUF_ (TP_*ASTR_) // 4480 shorts per A buffer
#define DRB_  116         // dr LDS t-stride BYTES (4-aligned, 29 dwords)

#define START_T  10
#define CODING_T 10
#define REMAIN_T 5

typedef __attribute__((ext_vector_type(8))) short short8v;
typedef __attribute__((ext_vector_type(8))) unsigned short ushort8v;
typedef __attribute__((ext_vector_type(4))) float f32x4;
typedef __attribute__((ext_vector_type(2))) float f32x2;

__device__ __forceinline__ float sigmoidf_(float x) {
  return 1.0f / (1.0f + expf(-x));
}

// HW packed cvt f32x2 -> 2 bf16 (RTNE)
__device__ __forceinline__ unsigned cvtpk(float lo, float hi) {
  unsigned r;
  asm("v_cvt_pk_bf16_f32 %0, %1, %2" : "=v"(r) : "v"(lo), "v"(hi));
  return r;
}

// HW packed cvt 4 f32 -> 4 fp8 e4m3 bytes (t-order), via builtins
__device__ __forceinline__ unsigned cvtpk_fp8x4(float f0, float f1, float f2, float f3) {
  int r = __builtin_amdgcn_cvt_pk_fp8_f32(f0, f1, 0, false);   // bytes 0,1
  r = __builtin_amdgcn_cvt_pk_fp8_f32(f2, f3, r, true);        // bytes 2,3
  return (unsigned)r;
}

__device__ __forceinline__ unsigned short f2bf(float f) {
  unsigned u = __float_as_uint(f);
  u = (u + 0x7fffu + ((u >> 16) & 1u)) >> 16;   // RTNE
  return (unsigned short)u;
}

// ---------- convert weights fp32 -> padded bf16 Wb[2][512][352] ----------
__global__ __launch_bounds__(256) void convert_w(
    const float* __restrict__ W1, const float* __restrict__ W2,
    unsigned short* __restrict__ wb)
{
  const int idx = blockIdx.x * 256 + threadIdx.x;  // 8-elem chunk; 45056 total
  const int ph  = idx / (H_ * (KP_ / 8));
  const int rem = idx % (H_ * (KP_ / 8));
  const int h   = rem / (KP_ / 8);
  const int cc  = (rem % (KP_ / 8)) * 8;
  ushort8v v;
#pragma unroll
  for (int j = 0; j < 8; ++j) {
    const int kk = cc + j;
    float f;
    if (ph == 0) f = (kk < HALF_) ? W1[(size_t)h * HALF_ + kk] : 0.0f;
    else         f = (kk >= 2)    ? W2[(size_t)h * HALF_ + kk - 2] : 0.0f;
    v[j] = f2bf(f);
  }
  *reinterpret_cast<ushort8v*>(wb + (((size_t)ph * H_ + h) * KP_) + cc) = v;
}

// ---------- fused: per-b drive GEMM + LIF scan -> bitpacked spikes ----------
// One 1024-thread block per b (exact round-9 GEMM; scan emits 4 u32 per h).
__global__ __launch_bounds__(1024, 4) void fused_drive_scan(
    const float* __restrict__ input, const unsigned short* __restrict__ Wb,
    const float* __restrict__ v_init, const float* __restrict__ tau_n,
    const float* __restrict__ tau_m, unsigned* __restrict__ spk)
{
  __shared__ __align__(16) unsigned short As[2 * ABUF_];   // 17920 B
  __shared__ __align__(16) unsigned char d1c[H_ * DRB_];   // 59392 B (fp8)
  __shared__ __align__(16) unsigned char d2c[H_ * DRB_];   // 59392 B (fp8)

  const int tid  = threadIdx.x;
  const int lane = tid & 63;
  const int w    = tid >> 6;           // 0..15
  const int b    = blockIdx.x;         // 0..499

  // A staging: thread tid<896 -> row sr = tid>>3, 4-float chunk so = (tid&7)*4
  const int sr = tid >> 3;
  const int so = (tid & 7) * 4;
  const bool stLd = (tid < 800);                    // sr < 100
  const bool stZr = (tid >= 800) && (tid < 896);    // pad rows 100..111
  const float* aBase = input + ((size_t)b * T_ + (stLd ? sr : 0)) * I_ + so;
  unsigned short* aDst = As + sr * ASTR_ + so;

  // B fragment addressing (direct global; Wb is L2-resident)
  const int brow = w * 32 + (lane & 15);
  const int kcS  = (lane >> 4) * 8;
  const unsigned short* bBase0 = Wb + (size_t)brow * KP_ + kcS;
  const unsigned short* bBase1 = Wb + (size_t)(brow + 16) * KP_ + kcS;
  const int arow = lane & 15;

  f32x4 acc[7][2];
#pragma unroll
  for (int i = 0; i < 7; ++i) {
    acc[i][0] = f32x4{0.f, 0.f, 0.f, 0.f};
    acc[i][1] = f32x4{0.f, 0.f, 0.f, 0.f};
  }

  float4 aR;
  short8v bC0, bC1, bN0, bN1;

  // ---- prologue: zero pad rows (both bufs); stage A(0); prefetch A(1), B ----
  if (stZr) {
    const uint2 z = {0, 0};
    *(uint2*)(aDst) = z;
    *(uint2*)(aDst + ABUF_) = z;
  }
  if (stLd) aR = *(const float4*)(aBase);
  bC0 = *reinterpret_cast<const short8v*>(bBase0);
  bC1 = *reinterpret_cast<const short8v*>(bBase1);
  bN0 = *reinterpret_cast<const short8v*>(bBase0 + 32);
  bN1 = *reinterpret_cast<const short8v*>(bBase1 + 32);
  if (stLd) {
    const uint2 p = {cvtpk(aR.x, aR.y), cvtpk(aR.z, aR.w)};
    *(uint2*)(aDst) = p;
    aR = *(const float4*)(aBase + 32);   // A(1)
  }
  asm volatile("s_waitcnt lgkmcnt(0)" ::: "memory");
  __builtin_amdgcn_s_barrier();
  asm volatile("" ::: "memory");

#pragma unroll 1
  for (int k = 0; k < 22; ++k) {
    const int buf  = (k & 1) * ABUF_;
    const int nbuf = ((k + 1) & 1) * ABUF_;
    // ---- A fragments + MFMA ----
    short8v a[7];
#pragma unroll
    for (int i = 0; i < 7; ++i)
      a[i] = *reinterpret_cast<const short8v*>(As + buf + (arow + i * 16) * ASTR_ + kcS);
#pragma unroll
    for (int i = 0; i < 7; ++i) {
      acc[i][0] = __builtin_amdgcn_mfma_f32_16x16x32_bf16(a[i], bC0, acc[i][0], 0, 0, 0);
      acc[i][1] = __builtin_amdgcn_mfma_f32_16x16x32_bf16(a[i], bC1, acc[i][1], 0, 0, 0);
    }
    bC0 = bN0; bC1 = bN1;
    // ---- stage A(k+1) from in-flight aR; prefetch A(k+2), B(k+2) ----
    if (k < 21 && stLd) {
      const uint2 p = {cvtpk(aR.x, aR.y), cvtpk(aR.z, aR.w)};
      *(uint2*)(aDst + nbuf) = p;
    }
    if (k < 20 && stLd) {
      const int kn  = k + 2;
      const int ph  = (kn >= 11);
      const int k0  = (kn - ph * 11) * 32;
      aR = *(const float4*)(aBase + (ph ? 348 : 0) + k0);
    }
    if (k < 20) {
      const int kb  = k + 2;
      const int phb = (kb >= 11);
      const size_t bo = (size_t)phb * H_ * KP_ + (kb - phb * 11) * 32;
      bN0 = *reinterpret_cast<const short8v*>(bBase0 + bo);
      bN1 = *reinterpret_cast<const short8v*>(bBase1 + bo);
    }
    // ---- phase boundary: dump acc -> fp8 dr LDS, reset ----
    if (k == 10 || k == 21) {
      unsigned char* ds = (k == 10) ? d1c : d2c;
#pragma unroll
      for (int i = 0; i < 7; ++i) {
        const int tb = i * 16 + ((lane >> 4) << 2);
#pragma unroll
        for (int j = 0; j < 2; ++j) {
          const int hl = w * 32 + j * 16 + (lane & 15);
          const unsigned r =
              cvtpk_fp8x4(acc[i][j][0], acc[i][j][1], acc[i][j][2], acc[i][j][3]);
          *(unsigned*)(ds + hl * DRB_ + tb) = r;
          acc[i][j] = f32x4{0.f, 0.f, 0.f, 0.f};
        }
      }
    }
    asm volatile("s_waitcnt lgkmcnt(0)" ::: "memory");
    __builtin_amdgcn_s_barrier();
    asm volatile("" ::: "memory");
  }

  // ---- in-block LIF scan: thread = one h; bitpack spikes -> global u32 ----
  if (tid < H_) {
    const int hg = tid;
    const float beta1 = sigmoidf_(tau_n[hg]);
    const float beta2 = sigmoidf_(tau_n[H_ + hg]);
    const float alpha = sigmoidf_(tau_m[hg]);
    const float ob1 = 1.0f - beta1, ob2 = 1.0f - beta2, oa = 1.0f - alpha;

    float d1 = 0.0f, d2 = 0.0f, s = 0.0f;
    float v = v_init[(size_t)b * H_ + hg];
    const unsigned char* r1 = d1c + hg * DRB_;
    const unsigned char* r2 = d2c + hg * DRB_;
    unsigned* sp = spk + (size_t)b * 4 * H_ + hg;
#pragma unroll
    for (int wi = 0; wi < 4; ++wi) {
      unsigned bits = 0;
#pragma unroll
      for (int cc = 0; cc < 8; ++cc) {
        if (wi == 3 && cc >= 1) break;            // t 96..99 only
        const int c = wi * 8 + cc;
        const unsigned u1 = *(const unsigned*)(r1 + c * 4);
        const unsigned u2 = *(const unsigned*)(r2 + c * 4);
        const f32x2 a1 = __builtin_amdgcn_cvt_pk_f32_fp8((int)u1, false);
        const f32x2 b1 = __builtin_amdgcn_cvt_pk_f32_fp8((int)u1, true);
        const f32x2 a2 = __builtin_amdgcn_cvt_pk_f32_fp8((int)u2, false);
        const f32x2 b2 = __builtin_amdgcn_cvt_pk_f32_fp8((int)u2, true);
        const float f1[4] = {a1[0], a1[1], b1[0], b1[1]};
        const float f2[4] = {a2[0], a2[1], b2[0], b2[1]};
#pragma unroll
        for (int j = 0; j < 4; ++j) {
          d1 = beta1 * d1 + ob1 * f1[j];
          d2 = beta2 * d2 + ob2 * f2[j];
          v = alpha * v + oa * (d1 + d2) - s;     // V_TH = 1
          const bool spkb = (v > 1.0f);
          s = spkb ? 1.0f : 0.0f;
          bits |= ((unsigned)spkb) << (cc * 4 + j);
        }
      }
      sp[wi * H_] = bits;
    }
  }
}

// ---------- output GEMM + loss per b (256 threads, 4 waves) ----------
__global__ __launch_bounds__(256) void out_loss(
    const unsigned* __restrict__ spk, const float* __restrict__ Wout,
    const float* __restrict__ bout, const int* __restrict__ target,
    float* __restrict__ oh, float* __restrict__ partials)
{
  __shared__ unsigned sb_lds[4 * H_];   // 8 KB: this b's spike planes
  __shared__ float rrowAll[4][24];
  __shared__ float redL[4], redC[4];

  const int tid  = threadIdx.x;
  const int lane = tid & 63;
  const int w    = tid >> 6;            // 0..3
  const int b    = blockIdx.x;

  // stage spike planes: 2048 u32 / 256 thr = 8 each (coalesced uint4 x2)
  {
    const unsigned* src = spk + (size_t)b * 4 * H_ + tid * 8;
    const uint4 v0 = *(const uint4*)(src);
    const uint4 v1 = *(const uint4*)(src + 4);
    *(uint4*)(sb_lds + tid * 8)     = v0;
    *(uint4*)(sb_lds + tid * 8 + 4) = v1;
  }
  __syncthreads();

  float* rrow = rrowAll[w];
  float lossAcc = 0.0f, corrAcc = 0.0f;
  const int hbase = lane * 8;
#pragma unroll 1
  for (int t = w; t < T_; t += 4) {
    const unsigned* sb = sb_lds + (t >> 5) * H_ + hbase;
    const uint4 wa = *(const uint4*)(sb);
    const uint4 wb2 = *(const uint4*)(sb + 4);
    const unsigned sel = t & 31;
    const unsigned msk = ((wa.x >> sel) & 1u)        | (((wa.y >> sel) & 1u) << 1) |
                         (((wa.z >> sel) & 1u) << 2) | (((wa.w >> sel) & 1u) << 3) |
                         (((wb2.x >> sel) & 1u) << 4)| (((wb2.y >> sel) & 1u) << 5) |
                         (((wb2.z >> sel) & 1u) << 6)| (((wb2.w >> sel) & 1u) << 7);

    // 5 chunks x 4 outputs: few live registers
#pragma unroll 1
    for (int c = 0; c < 5; ++c) {
      float a0 = 0.f, a1 = 0.f, a2 = 0.f, a3 = 0.f;
      const float* Wc = Wout + (c * 4) * H_ + hbase;
#pragma unroll
      for (int j = 0; j < 8; ++j) {
        if ((msk >> j) & 1u) {
          a0 += Wc[j];
          a1 += Wc[H_ + j];
          a2 += Wc[2 * H_ + j];
          a3 += Wc[3 * H_ + j];
        }
      }
#pragma unroll
      for (int off = 32; off; off >>= 1) {
        a0 += __shfl_xor(a0, off);
        a1 += __shfl_xor(a1, off);
        a2 += __shfl_xor(a2, off);
        a3 += __shfl_xor(a3, off);
      }
      if (lane == 0) {
        rrow[c * 4 + 0] = a0 + bout[c * 4 + 0];
        rrow[c * 4 + 1] = a1 + bout[c * 4 + 1];
        rrow[c * 4 + 2] = a2 + bout[c * 4 + 2];
        rrow[c * 4 + 3] = a3 + bout[c * 4 + 3];
      }
    }
    if (lane < O_) oh[((size_t)b * T_ + t) * O_ + lane] = rrow[lane];

    const bool maskv = (t > START_T) && (((t - START_T) % (CODING_T + REMAIN_T)) > REMAIN_T);
    if (maskv && lane == 0) {
      const int tgt = target[(size_t)b * T_ + t];
      float m = rrow[0];
      int pred = 0;
#pragma unroll
      for (int o = 1; o < O_; ++o) {
        const float v = rrow[o];
        if (v > m) { m = v; pred = o; }
      }
      float S = 0.0f, etgt = 0.0f;
#pragma unroll
      for (int o = 0; o < O_; ++o) {
        const float eo = expf(rrow[o] - m);
        S += eo;
        if (o == tgt) etgt = eo;
      }
      const float inv = 1.0f / S;           // = max(p)
      float S2 = 0.0f;
#pragma unroll
      for (int o = 0; o < O_; ++o) S2 += expf(expf(rrow[o] - m) * inv - inv);
      lossAcc += (inv + logf(S2) - etgt * inv) * (1.0f / (float)B_);
      corrAcc += (pred == tgt) ? 1.0f : 0.0f;
    }
  }
  if (lane == 0) { redL[w] = lossAcc; redC[w] = corrAcc; }
  __syncthreads();
  if (tid == 0) {
    partials[b]      = redL[0] + redL[1] + redL[2] + redL[3];
    partials[B_ + b] = redC[0] + redC[1] + redC[2] + redC[3];
  }
}

__global__ __launch_bounds__(256) void loss_final(
    const float* __restrict__ partials, float* __restrict__ out, float samples)
{
  float a = 0.0f, c = 0.0f;
  for (int i = threadIdx.x; i < B_; i += 256) { a += partials[i]; c += partials[B_ + i]; }
  __shared__ float sl[256], sc[256];
  sl[threadIdx.x] = a; sc[threadIdx.x] = c;
  __syncthreads();
  for (int s = 128; s > 0; s >>= 1) {
    if (threadIdx.x < s) {
      sl[threadIdx.x] += sl[threadIdx.x + s];
      sc[threadIdx.x] += sc[threadIdx.x + s];
    }
    __syncthreads();
  }
  if (threadIdx.x == 0) {
    out[0] = sl[0];
    out[1 + (size_t)M_ * O_] = sc[0];
    out[2 + (size_t)M_ * O_] = samples;
  }
}

extern "C" void kernel_launch(void* const* d_in, const int* in_sizes, int n_in,
                              void* d_out, int out_size, void* d_ws, size_t ws_size,
                              hipStream_t stream) {
  const float* input  = (const float*)d_in[0];
  const int*   target = (const int*)d_in[1];
  const float* v_init = (const float*)d_in[2];
  const float* W1     = (const float*)d_in[3];
  const float* W2     = (const float*)d_in[4];
  const float* tau_n  = (const float*)d_in[5];
  const float* tau_m  = (const float*)d_in[6];
  const float* Wout   = (const float*)d_in[7];
  const float* bout   = (const float*)d_in[8];
  float* out = (float*)d_out;
  float* oh  = out + 1;

  // ws layout: Wb[2*512*352 bf16] spk[500*4*512 u32] partials[2*B_ f32]
  unsigned short* Wb = (unsigned short*)d_ws;
  unsigned* spk = (unsigned*)(Wb + (size_t)2 * H_ * KP_);
  float* partials = (float*)(spk + (size_t)B_ * 4 * H_);

  hipLaunchKernelGGL(convert_w, dim3((2 * H_ * KP_ / 8) / 256), dim3(256), 0, stream,
                     W1, W2, Wb);

  hipLaunchKernelGGL(fused_drive_scan, dim3(B_), dim3(1024), 0, stream,
                     input, Wb, v_init, tau_n, tau_m, spk);

  hipLaunchKernelGGL(out_loss, dim3(B_), dim3(256), 0, stream,
                     spk, Wout, bout, target, oh, partials);

  int mcount = 0;
  for (int t = 0; t < T_; ++t)
    if (t > START_T && ((t - START_T) % (CODING_T + REMAIN_T)) > REMAIN_T) mcount++;
  hipLaunchKernelGGL(loss_final, dim3(1), dim3(256), 0, stream, partials,
                     out, (float)(mcount * B_));
}

// Round 14
// 256.555 us; speedup vs baseline: 1.1882x; 1.1882x over previous
//
#include <hip/hip_runtime.h>
#include <hip/hip_bf16.h>
#include <math.h>

#define B_    500
#define T_    100
#define I_    700
#define HALF_ 350
#define H_    512
#define O_    20
#define M_    (B_*T_)     // 50000
#define BH_   (B_*H_)     // 256000
#define TP_   112         // T padded to 7*16
#define KP_   352         // padded K per phase
#define ASTR_ 40          // A LDS row stride shorts (80B)
#define ABUF_ (TP_*ASTR_) // 4480 shorts per A buffer
#define DRB_  116         // dr LDS t-stride BYTES (4-aligned, 29 dwords)

#define START_T  10
#define CODING_T 10
#define REMAIN_T 5

typedef __attribute__((ext_vector_type(8))) short short8v;
typedef __attribute__((ext_vector_type(8))) unsigned short ushort8v;
typedef __attribute__((ext_vector_type(4))) float f32x4;
typedef __attribute__((ext_vector_type(2))) float f32x2;

__device__ __forceinline__ float sigmoidf_(float x) {
  return 1.0f / (1.0f + expf(-x));
}

// HW packed cvt f32x2 -> 2 bf16 (RTNE)
__device__ __forceinline__ unsigned cvtpk(float lo, float hi) {
  unsigned r;
  asm("v_cvt_pk_bf16_f32 %0, %1, %2" : "=v"(r) : "v"(lo), "v"(hi));
  return r;
}

// HW packed cvt 4 f32 -> 4 fp8 e4m3 bytes (t-order), via builtins
__device__ __forceinline__ unsigned cvtpk_fp8x4(float f0, float f1, float f2, float f3) {
  int r = __builtin_amdgcn_cvt_pk_fp8_f32(f0, f1, 0, false);   // bytes 0,1
  r = __builtin_amdgcn_cvt_pk_fp8_f32(f2, f3, r, true);        // bytes 2,3
  return (unsigned)r;
}

__device__ __forceinline__ unsigned short f2bf(float f) {
  unsigned u = __float_as_uint(f);
  u = (u + 0x7fffu + ((u >> 16) & 1u)) >> 16;   // RTNE
  return (unsigned short)u;
}

// ---------- convert weights fp32 -> padded bf16 Wb[2][512][352] ----------
__global__ __launch_bounds__(256) void convert_w(
    const float* __restrict__ W1, const float* __restrict__ W2,
    unsigned short* __restrict__ wb)
{
  const int idx = blockIdx.x * 256 + threadIdx.x;  // 8-elem chunk; 45056 total
  const int ph  = idx / (H_ * (KP_ / 8));
  const int rem = idx % (H_ * (KP_ / 8));
  const int h   = rem / (KP_ / 8);
  const int cc  = (rem % (KP_ / 8)) * 8;
  ushort8v v;
#pragma unroll
  for (int j = 0; j < 8; ++j) {
    const int kk = cc + j;
    float f;
    if (ph == 0) f = (kk < HALF_) ? W1[(size_t)h * HALF_ + kk] : 0.0f;
    else         f = (kk >= 2)    ? W2[(size_t)h * HALF_ + kk - 2] : 0.0f;
    v[j] = f2bf(f);
  }
  *reinterpret_cast<ushort8v*>(wb + (((size_t)ph * H_ + h) * KP_) + cc) = v;
}

// ---------- fused: per-b drive GEMM (all 512 h) + in-LDS LIF scan ----------
// EXACT round-9 structure (52 VGPR, no spill). Spike layout: [b][t][h] bytes.
__global__ __launch_bounds__(1024, 4) void fused_drive_scan(
    const float* __restrict__ input, const unsigned short* __restrict__ Wb,
    const float* __restrict__ v_init, const float* __restrict__ tau_n,
    const float* __restrict__ tau_m, unsigned char* __restrict__ spikes)
{
  __shared__ __align__(16) unsigned short As[2 * ABUF_];   // 17920 B
  __shared__ __align__(4) unsigned char d1c[H_ * DRB_];    // 59392 B (fp8)
  __shared__ __align__(4) unsigned char d2c[H_ * DRB_];    // 59392 B (fp8)

  const int tid  = threadIdx.x;
  const int lane = tid & 63;
  const int w    = tid >> 6;           // 0..15
  const int b    = blockIdx.x;         // 0..499

  // A staging: thread tid<896 -> row sr = tid>>3, 4-float chunk so = (tid&7)*4
  const int sr = tid >> 3;
  const int so = (tid & 7) * 4;
  const bool stLd = (tid < 800);                    // sr < 100
  const bool stZr = (tid >= 800) && (tid < 896);    // pad rows 100..111
  const float* aBase = input + ((size_t)b * T_ + (stLd ? sr : 0)) * I_ + so;
  unsigned short* aDst = As + sr * ASTR_ + so;

  // B fragment addressing (direct global; Wb is L2-resident)
  const int brow = w * 32 + (lane & 15);
  const int kcS  = (lane >> 4) * 8;
  const unsigned short* bBase0 = Wb + (size_t)brow * KP_ + kcS;
  const unsigned short* bBase1 = Wb + (size_t)(brow + 16) * KP_ + kcS;
  const int arow = lane & 15;

  f32x4 acc[7][2];
#pragma unroll
  for (int i = 0; i < 7; ++i) {
    acc[i][0] = f32x4{0.f, 0.f, 0.f, 0.f};
    acc[i][1] = f32x4{0.f, 0.f, 0.f, 0.f};
  }

  float4 aR;
  short8v bC0, bC1, bN0, bN1;

  // ---- prologue: zero pad rows (both bufs); stage A(0); prefetch A(1), B ----
  if (stZr) {
    const uint2 z = {0, 0};
    *(uint2*)(aDst) = z;
    *(uint2*)(aDst + ABUF_) = z;
  }
  if (stLd) aR = *(const float4*)(aBase);
  bC0 = *reinterpret_cast<const short8v*>(bBase0);
  bC1 = *reinterpret_cast<const short8v*>(bBase1);
  bN0 = *reinterpret_cast<const short8v*>(bBase0 + 32);
  bN1 = *reinterpret_cast<const short8v*>(bBase1 + 32);
  if (stLd) {
    const uint2 p = {cvtpk(aR.x, aR.y), cvtpk(aR.z, aR.w)};
    *(uint2*)(aDst) = p;
    aR = *(const float4*)(aBase + 32);   // A(1)
  }
  asm volatile("s_waitcnt lgkmcnt(0)" ::: "memory");
  __builtin_amdgcn_s_barrier();
  asm volatile("" ::: "memory");

#pragma unroll 1
  for (int k = 0; k < 22; ++k) {
    const int buf  = (k & 1) * ABUF_;
    const int nbuf = ((k + 1) & 1) * ABUF_;
    // ---- A fragments + MFMA ----
    short8v a[7];
#pragma unroll
    for (int i = 0; i < 7; ++i)
      a[i] = *reinterpret_cast<const short8v*>(As + buf + (arow + i * 16) * ASTR_ + kcS);
#pragma unroll
    for (int i = 0; i < 7; ++i) {
      acc[i][0] = __builtin_amdgcn_mfma_f32_16x16x32_bf16(a[i], bC0, acc[i][0], 0, 0, 0);
      acc[i][1] = __builtin_amdgcn_mfma_f32_16x16x32_bf16(a[i], bC1, acc[i][1], 0, 0, 0);
    }
    bC0 = bN0; bC1 = bN1;
    // ---- stage A(k+1) from in-flight aR; prefetch A(k+2), B(k+2) ----
    if (k < 21 && stLd) {
      const uint2 p = {cvtpk(aR.x, aR.y), cvtpk(aR.z, aR.w)};
      *(uint2*)(aDst + nbuf) = p;
    }
    if (k < 20 && stLd) {
      const int kn  = k + 2;
      const int ph  = (kn >= 11);
      const int k0  = (kn - ph * 11) * 32;
      aR = *(const float4*)(aBase + (ph ? 348 : 0) + k0);
    }
    if (k < 20) {
      const int kb  = k + 2;
      const int phb = (kb >= 11);
      const size_t bo = (size_t)phb * H_ * KP_ + (kb - phb * 11) * 32;
      bN0 = *reinterpret_cast<const short8v*>(bBase0 + bo);
      bN1 = *reinterpret_cast<const short8v*>(bBase1 + bo);
    }
    // ---- phase boundary: dump acc -> fp8 dr LDS, reset ----
    if (k == 10 || k == 21) {
      unsigned char* ds = (k == 10) ? d1c : d2c;
#pragma unroll
      for (int i = 0; i < 7; ++i) {
        const int tb = i * 16 + ((lane >> 4) << 2);
#pragma unroll
        for (int j = 0; j < 2; ++j) {
          const int hl = w * 32 + j * 16 + (lane & 15);
          const unsigned r =
              cvtpk_fp8x4(acc[i][j][0], acc[i][j][1], acc[i][j][2], acc[i][j][3]);
          *(unsigned*)(ds + hl * DRB_ + tb) = r;
          acc[i][j] = f32x4{0.f, 0.f, 0.f, 0.f};
        }
      }
    }
    asm volatile("s_waitcnt lgkmcnt(0)" ::: "memory");
    __builtin_amdgcn_s_barrier();
    asm volatile("" ::: "memory");
  }

  // ---- in-block LIF scan: thread = one h column (round-9 structure) ----
  if (tid < H_) {
    const int hg = tid;
    const float beta1 = sigmoidf_(tau_n[hg]);
    const float beta2 = sigmoidf_(tau_n[H_ + hg]);
    const float alpha = sigmoidf_(tau_m[hg]);
    const float ob1 = 1.0f - beta1, ob2 = 1.0f - beta2, oa = 1.0f - alpha;

    float d1 = 0.0f, d2 = 0.0f, s = 0.0f;
    float v = v_init[(size_t)b * H_ + hg];
    const unsigned char* r1 = d1c + hg * DRB_;
    const unsigned char* r2 = d2c + hg * DRB_;
    unsigned char* sp = spikes + (size_t)b * (T_ * H_) + hg;   // [b][t][h]
#pragma unroll 1
    for (int c = 0; c < 25; ++c) {                    // 25 x 4 = 100 steps
      const unsigned u1 = *(const unsigned*)(r1 + c * 4);
      const unsigned u2 = *(const unsigned*)(r2 + c * 4);
      const f32x2 a1 = __builtin_amdgcn_cvt_pk_f32_fp8((int)u1, false);
      const f32x2 b1 = __builtin_amdgcn_cvt_pk_f32_fp8((int)u1, true);
      const f32x2 a2 = __builtin_amdgcn_cvt_pk_f32_fp8((int)u2, false);
      const f32x2 b2 = __builtin_amdgcn_cvt_pk_f32_fp8((int)u2, true);
      const float f1[4] = {a1[0], a1[1], b1[0], b1[1]};
      const float f2[4] = {a2[0], a2[1], b2[0], b2[1]};
#pragma unroll
      for (int j = 0; j < 4; ++j) {
        d1 = beta1 * d1 + ob1 * f1[j];
        d2 = beta2 * d2 + ob2 * f2[j];
        v = alpha * v + oa * (d1 + d2) - s;   // V_TH = 1
        s = (v > 1.0f) ? 1.0f : 0.0f;
        sp[(size_t)(c * 4 + j) * H_] = (unsigned char)s;
      }
    }
  }
}

// ---------- per-b output GEMM + loss (256 threads, LDS-staged spikes) ----------
__global__ __launch_bounds__(256) void out_loss(
    const unsigned char* __restrict__ spikes, const float* __restrict__ Wout,
    const float* __restrict__ bout, const int* __restrict__ target,
    float* __restrict__ oh, float* __restrict__ partials)
{
  __shared__ __align__(16) unsigned char sp_lds[T_ * H_];   // 51200 B
  __shared__ float redL[4], redC[4];

  const int tid  = threadIdx.x;
  const int lane = tid & 63;
  const int w    = tid >> 6;            // 0..3
  const int b    = blockIdx.x;

  // stage this b's spike plane: 3200 uint4, coalesced
  {
    const uint4* src = (const uint4*)(spikes + (size_t)b * (T_ * H_));
    uint4* dst = (uint4*)sp_lds;
#pragma unroll 1
    for (int i = tid; i < (T_ * H_) / 16; i += 256) dst[i] = src[i];
  }
  __syncthreads();

  float lossAcc = 0.0f, corrAcc = 0.0f;
#pragma unroll 1
  for (int t = w; t < T_; t += 4) {
    const uint2 sv = *(const uint2*)(sp_lds + t * H_ + lane * 8);
    float acc[O_];
#pragma unroll
    for (int o = 0; o < O_; ++o) acc[o] = 0.0f;
#pragma unroll
    for (int j = 0; j < 8; ++j) {
      const unsigned sb = ((j < 4) ? (sv.x >> (8 * j)) : (sv.y >> (8 * (j - 4)))) & 255u;
      if (sb) {
        const int hh = lane * 8 + j;
#pragma unroll
        for (int o = 0; o < O_; ++o) acc[o] += Wout[o * H_ + hh];
      }
    }
    // butterfly: every lane ends with the full sums (wave-parallel epilogue)
#pragma unroll
    for (int o = 0; o < O_; ++o) {
#pragma unroll
      for (int off = 32; off; off >>= 1) acc[o] += __shfl_xor(acc[o], off);
      acc[o] += bout[o];
    }
    if (lane == 0) {
      float* orow = oh + ((size_t)b * T_ + t) * O_;
#pragma unroll
      for (int o = 0; o < O_; ++o) orow[o] = acc[o];
    }
    const bool maskv = (t > START_T) && (((t - START_T) % (CODING_T + REMAIN_T)) > REMAIN_T);
    if (maskv) {
      const int tgt = target[(size_t)b * T_ + t];
      float m = acc[0];
      int pred = 0;
#pragma unroll
      for (int o = 1; o < O_; ++o) { if (acc[o] > m) { m = acc[o]; pred = o; } }
      float S = 0.0f, etgt = 0.0f;
#pragma unroll
      for (int o = 0; o < O_; ++o) {
        const float eo = expf(acc[o] - m);
        S += eo;
        if (o == tgt) etgt = eo;
      }
      const float inv = 1.0f / S;           // = max(p)
      float S2 = 0.0f;
#pragma unroll
      for (int o = 0; o < O_; ++o) S2 += expf(expf(acc[o] - m) * inv - inv);
      lossAcc += (inv + logf(S2) - etgt * inv) * (1.0f / (float)B_);
      corrAcc += (pred == tgt) ? 1.0f : 0.0f;
    }
  }
  if (lane == 0) { redL[w] = lossAcc; redC[w] = corrAcc; }
  __syncthreads();
  if (tid == 0) {
    partials[b]      = redL[0] + redL[1] + redL[2] + redL[3];
    partials[B_ + b] = redC[0] + redC[1] + redC[2] + redC[3];
  }
}

__global__ __launch_bounds__(256) void loss_final(
    const float* __restrict__ partials, float* __restrict__ out, float samples)
{
  float a = 0.0f, c = 0.0f;
  for (int i = threadIdx.x; i < B_; i += 256) { a += partials[i]; c += partials[B_ + i]; }
  __shared__ float sl[256], sc[256];
  sl[threadIdx.x] = a; sc[threadIdx.x] = c;
  __syncthreads();
  for (int s = 128; s > 0; s >>= 1) {
    if (threadIdx.x < s) {
      sl[threadIdx.x] += sl[threadIdx.x + s];
      sc[threadIdx.x] += sc[threadIdx.x + s];
    }
    __syncthreads();
  }
  if (threadIdx.x == 0) {
    out[0] = sl[0];
    out[1 + (size_t)M_ * O_] = sc[0];
    out[2 + (size_t)M_ * O_] = samples;
  }
}

extern "C" void kernel_launch(void* const* d_in, const int* in_sizes, int n_in,
                              void* d_out, int out_size, void* d_ws, size_t ws_size,
                              hipStream_t stream) {
  const float* input  = (const float*)d_in[0];
  const int*   target = (const int*)d_in[1];
  const float* v_init = (const float*)d_in[2];
  const float* W1     = (const float*)d_in[3];
  const float* W2     = (const float*)d_in[4];
  const float* tau_n  = (const float*)d_in[5];
  const float* tau_m  = (const float*)d_in[6];
  const float* Wout   = (const float*)d_in[7];
  const float* bout   = (const float*)d_in[8];
  float* out = (float*)d_out;
  float* oh  = out + 1;

  // ws layout: Wb[2*512*352 bf16] spikes[500*100*512 u8] partials[2*B_ f32]
  unsigned short* Wb = (unsigned short*)d_ws;
  unsigned char* spikes = (unsigned char*)(Wb + (size_t)2 * H_ * KP_);
  float* partials = (float*)(spikes + (size_t)B_ * T_ * H_);

  hipLaunchKernelGGL(convert_w, dim3((2 * H_ * KP_ / 8) / 256), dim3(256), 0, stream,
                     W1, W2, Wb);

  hipLaunchKernelGGL(fused_drive_scan, dim3(B_), dim3(1024), 0, stream,
                     input, Wb, v_init, tau_n, tau_m, spikes);

  hipLaunchKernelGGL(out_loss, dim3(B_), dim3(256), 0, stream,
                     spikes, Wout, bout, target, oh, partials);

  int mcount = 0;
  for (int t = 0; t < T_; ++t)
    if (t > START_T && ((t - START_T) % (CODING_T + REMAIN_T)) > REMAIN_T) mcount++;
  hipLaunchKernelGGL(loss_final, dim3(1), dim3(256), 0, stream, partials,
                     out, (float)(mcount * B_));
}

// Round 15
// 162.570 us; speedup vs baseline: 1.8751x; 1.5781x over previous
//
#include <hip/hip_runtime.h>
#include <hip/hip_bf16.h>
#include <math.h>

#define B_    500
#define T_    100
#define I_    700
#define HALF_ 350
#define H_    512
#define O_    20
#define M_    (B_*T_)     // 50000
#define BH_   (B_*H_)     // 256000
#define TP_   112         // T padded to 7*16
#define KP_   352         // padded K per phase
#define ASTR_ 40          // A LDS row stride shorts (80B)
#define ABUF_ (TP_*ASTR_) // 4480 shorts per A buffer
#define DRB_  116         // dr LDS t-stride BYTES (4-aligned, 29 dwords)
#define NB_   12500       // out_loss blocks (4 (b,t) waves each)

#define START_T  10
#define CODING_T 10
#define REMAIN_T 5

typedef __attribute__((ext_vector_type(8))) short short8v;
typedef __attribute__((ext_vector_type(8))) unsigned short ushort8v;
typedef __attribute__((ext_vector_type(4))) float f32x4;
typedef __attribute__((ext_vector_type(2))) float f32x2;

__device__ __forceinline__ float sigmoidf_(float x) {
  return 1.0f / (1.0f + expf(-x));
}

// HW packed cvt f32x2 -> 2 bf16 (RTNE)
__device__ __forceinline__ unsigned cvtpk(float lo, float hi) {
  unsigned r;
  asm("v_cvt_pk_bf16_f32 %0, %1, %2" : "=v"(r) : "v"(lo), "v"(hi));
  return r;
}

// HW packed cvt 4 f32 -> 4 fp8 e4m3 bytes (t-order), via builtins
__device__ __forceinline__ unsigned cvtpk_fp8x4(float f0, float f1, float f2, float f3) {
  int r = __builtin_amdgcn_cvt_pk_fp8_f32(f0, f1, 0, false);   // bytes 0,1
  r = __builtin_amdgcn_cvt_pk_fp8_f32(f2, f3, r, true);        // bytes 2,3
  return (unsigned)r;
}

__device__ __forceinline__ unsigned short f2bf(float f) {
  unsigned u = __float_as_uint(f);
  u = (u + 0x7fffu + ((u >> 16) & 1u)) >> 16;   // RTNE
  return (unsigned short)u;
}

// ---------- convert weights fp32 -> padded bf16 Wb[2][512][352] ----------
__global__ __launch_bounds__(256) void convert_w(
    const float* __restrict__ W1, const float* __restrict__ W2,
    unsigned short* __restrict__ wb)
{
  const int idx = blockIdx.x * 256 + threadIdx.x;  // 8-elem chunk; 45056 total
  const int ph  = idx / (H_ * (KP_ / 8));
  const int rem = idx % (H_ * (KP_ / 8));
  const int h   = rem / (KP_ / 8);
  const int cc  = (rem % (KP_ / 8)) * 8;
  ushort8v v;
#pragma unroll
  for (int j = 0; j < 8; ++j) {
    const int kk = cc + j;
    float f;
    if (ph == 0) f = (kk < HALF_) ? W1[(size_t)h * HALF_ + kk] : 0.0f;
    else         f = (kk >= 2)    ? W2[(size_t)h * HALF_ + kk - 2] : 0.0f;
    v[j] = f2bf(f);
  }
  *reinterpret_cast<ushort8v*>(wb + (((size_t)ph * H_ + h) * KP_) + cc) = v;
}

// ---------- fused: per-b drive GEMM (all 512 h) + in-LDS LIF scan ----------
// EXACT round-14 structure (no spill). Spike layout: [b][t][h] bytes.
__global__ __launch_bounds__(1024, 4) void fused_drive_scan(
    const float* __restrict__ input, const unsigned short* __restrict__ Wb,
    const float* __restrict__ v_init, const float* __restrict__ tau_n,
    const float* __restrict__ tau_m, unsigned char* __restrict__ spikes)
{
  __shared__ __align__(16) unsigned short As[2 * ABUF_];   // 17920 B
  __shared__ __align__(4) unsigned char d1c[H_ * DRB_];    // 59392 B (fp8)
  __shared__ __align__(4) unsigned char d2c[H_ * DRB_];    // 59392 B (fp8)

  const int tid  = threadIdx.x;
  const int lane = tid & 63;
  const int w    = tid >> 6;           // 0..15
  const int b    = blockIdx.x;         // 0..499

  // A staging: thread tid<896 -> row sr = tid>>3, 4-float chunk so = (tid&7)*4
  const int sr = tid >> 3;
  const int so = (tid & 7) * 4;
  const bool stLd = (tid < 800);                    // sr < 100
  const bool stZr = (tid >= 800) && (tid < 896);    // pad rows 100..111
  const float* aBase = input + ((size_t)b * T_ + (stLd ? sr : 0)) * I_ + so;
  unsigned short* aDst = As + sr * ASTR_ + so;

  // B fragment addressing (direct global; Wb is L2-resident)
  const int brow = w * 32 + (lane & 15);
  const int kcS  = (lane >> 4) * 8;
  const unsigned short* bBase0 = Wb + (size_t)brow * KP_ + kcS;
  const unsigned short* bBase1 = Wb + (size_t)(brow + 16) * KP_ + kcS;
  const int arow = lane & 15;

  f32x4 acc[7][2];
#pragma unroll
  for (int i = 0; i < 7; ++i) {
    acc[i][0] = f32x4{0.f, 0.f, 0.f, 0.f};
    acc[i][1] = f32x4{0.f, 0.f, 0.f, 0.f};
  }

  float4 aR;
  short8v bC0, bC1, bN0, bN1;

  // ---- prologue: zero pad rows (both bufs); stage A(0); prefetch A(1), B ----
  if (stZr) {
    const uint2 z = {0, 0};
    *(uint2*)(aDst) = z;
    *(uint2*)(aDst + ABUF_) = z;
  }
  if (stLd) aR = *(const float4*)(aBase);
  bC0 = *reinterpret_cast<const short8v*>(bBase0);
  bC1 = *reinterpret_cast<const short8v*>(bBase1);
  bN0 = *reinterpret_cast<const short8v*>(bBase0 + 32);
  bN1 = *reinterpret_cast<const short8v*>(bBase1 + 32);
  if (stLd) {
    const uint2 p = {cvtpk(aR.x, aR.y), cvtpk(aR.z, aR.w)};
    *(uint2*)(aDst) = p;
    aR = *(const float4*)(aBase + 32);   // A(1)
  }
  asm volatile("s_waitcnt lgkmcnt(0)" ::: "memory");
  __builtin_amdgcn_s_barrier();
  asm volatile("" ::: "memory");

#pragma unroll 1
  for (int k = 0; k < 22; ++k) {
    const int buf  = (k & 1) * ABUF_;
    const int nbuf = ((k + 1) & 1) * ABUF_;
    // ---- A fragments + MFMA ----
    short8v a[7];
#pragma unroll
    for (int i = 0; i < 7; ++i)
      a[i] = *reinterpret_cast<const short8v*>(As + buf + (arow + i * 16) * ASTR_ + kcS);
#pragma unroll
    for (int i = 0; i < 7; ++i) {
      acc[i][0] = __builtin_amdgcn_mfma_f32_16x16x32_bf16(a[i], bC0, acc[i][0], 0, 0, 0);
      acc[i][1] = __builtin_amdgcn_mfma_f32_16x16x32_bf16(a[i], bC1, acc[i][1], 0, 0, 0);
    }
    bC0 = bN0; bC1 = bN1;
    // ---- stage A(k+1) from in-flight aR; prefetch A(k+2), B(k+2) ----
    if (k < 21 && stLd) {
      const uint2 p = {cvtpk(aR.x, aR.y), cvtpk(aR.z, aR.w)};
      *(uint2*)(aDst + nbuf) = p;
    }
    if (k < 20 && stLd) {
      const int kn  = k + 2;
      const int ph  = (kn >= 11);
      const int k0  = (kn - ph * 11) * 32;
      aR = *(const float4*)(aBase + (ph ? 348 : 0) + k0);
    }
    if (k < 20) {
      const int kb  = k + 2;
      const int phb = (kb >= 11);
      const size_t bo = (size_t)phb * H_ * KP_ + (kb - phb * 11) * 32;
      bN0 = *reinterpret_cast<const short8v*>(bBase0 + bo);
      bN1 = *reinterpret_cast<const short8v*>(bBase1 + bo);
    }
    // ---- phase boundary: dump acc -> fp8 dr LDS, reset ----
    if (k == 10 || k == 21) {
      unsigned char* ds = (k == 10) ? d1c : d2c;
#pragma unroll
      for (int i = 0; i < 7; ++i) {
        const int tb = i * 16 + ((lane >> 4) << 2);
#pragma unroll
        for (int j = 0; j < 2; ++j) {
          const int hl = w * 32 + j * 16 + (lane & 15);
          const unsigned r =
              cvtpk_fp8x4(acc[i][j][0], acc[i][j][1], acc[i][j][2], acc[i][j][3]);
          *(unsigned*)(ds + hl * DRB_ + tb) = r;
          acc[i][j] = f32x4{0.f, 0.f, 0.f, 0.f};
        }
      }
    }
    asm volatile("s_waitcnt lgkmcnt(0)" ::: "memory");
    __builtin_amdgcn_s_barrier();
    asm volatile("" ::: "memory");
  }

  // ---- in-block LIF scan: thread = one h column ----
  if (tid < H_) {
    const int hg = tid;
    const float beta1 = sigmoidf_(tau_n[hg]);
    const float beta2 = sigmoidf_(tau_n[H_ + hg]);
    const float alpha = sigmoidf_(tau_m[hg]);
    const float ob1 = 1.0f - beta1, ob2 = 1.0f - beta2, oa = 1.0f - alpha;

    float d1 = 0.0f, d2 = 0.0f, s = 0.0f;
    float v = v_init[(size_t)b * H_ + hg];
    const unsigned char* r1 = d1c + hg * DRB_;
    const unsigned char* r2 = d2c + hg * DRB_;
    unsigned char* sp = spikes + (size_t)b * (T_ * H_) + hg;   // [b][t][h]
#pragma unroll 1
    for (int c = 0; c < 25; ++c) {                    // 25 x 4 = 100 steps
      const unsigned u1 = *(const unsigned*)(r1 + c * 4);
      const unsigned u2 = *(const unsigned*)(r2 + c * 4);
      const f32x2 a1 = __builtin_amdgcn_cvt_pk_f32_fp8((int)u1, false);
      const f32x2 b1 = __builtin_amdgcn_cvt_pk_f32_fp8((int)u1, true);
      const f32x2 a2 = __builtin_amdgcn_cvt_pk_f32_fp8((int)u2, false);
      const f32x2 b2 = __builtin_amdgcn_cvt_pk_f32_fp8((int)u2, true);
      const float f1[4] = {a1[0], a1[1], b1[0], b1[1]};
      const float f2[4] = {a2[0], a2[1], b2[0], b2[1]};
#pragma unroll
      for (int j = 0; j < 4; ++j) {
        d1 = beta1 * d1 + ob1 * f1[j];
        d2 = beta2 * d2 + ob2 * f2[j];
        v = alpha * v + oa * (d1 + d2) - s;   // V_TH = 1
        s = (v > 1.0f) ? 1.0f : 0.0f;
        sp[(size_t)(c * 4 + j) * H_] = (unsigned char)s;
      }
    }
  }
}

// ---------- output GEMM + loss: wave per (b,t), 12500 blocks ----------
__global__ __launch_bounds__(256) void out_loss(
    const unsigned char* __restrict__ spikes, const float* __restrict__ Wout,
    const float* __restrict__ bout, const int* __restrict__ target,
    float* __restrict__ oh, float* __restrict__ partials)
{
  const int lane = threadIdx.x & 63;
  const int widx = threadIdx.x >> 6;
  const int bt = blockIdx.x * 4 + widx;          // == b*T_ + t
  const int t = bt % T_;

  // [b][t][h] layout: row contiguous, 512 B per wave (fully coalesced)
  const uint2 sv = *(const uint2*)(spikes + (size_t)bt * H_ + lane * 8);

  float acc[O_];
#pragma unroll
  for (int o = 0; o < O_; ++o) acc[o] = 0.0f;

#pragma unroll
  for (int j = 0; j < 8; ++j) {
    const unsigned sb = ((j < 4) ? (sv.x >> (8 * j)) : (sv.y >> (8 * (j - 4)))) & 255u;
    if (sb) {
      const int hh = lane * 8 + j;
#pragma unroll
      for (int o = 0; o < O_; ++o) acc[o] += Wout[o * H_ + hh];
    }
  }
  // butterfly: every lane ends with the full sums
#pragma unroll
  for (int o = 0; o < O_; ++o) {
#pragma unroll
    for (int off = 32; off; off >>= 1) acc[o] += __shfl_xor(acc[o], off);
    acc[o] += bout[o];
  }
  if (lane < O_) oh[(size_t)bt * O_ + lane] = acc[lane];

  __shared__ float sl[4], sc[4];
  float lossc = 0.0f, corr = 0.0f;
  const bool maskv = (t > START_T) && (((t - START_T) % (CODING_T + REMAIN_T)) > REMAIN_T);
  if (maskv) {
    // redundant wave-wide softmax (no divergence, no serial-lane section)
    const int tgt = target[bt];
    float m = acc[0];
    int pred = 0;
#pragma unroll
    for (int o = 1; o < O_; ++o) { if (acc[o] > m) { m = acc[o]; pred = o; } }
    float S = 0.0f, etgt = 0.0f;
#pragma unroll
    for (int o = 0; o < O_; ++o) {
      const float eo = expf(acc[o] - m);
      S += eo;
      if (o == tgt) etgt = eo;
    }
    const float inv = 1.0f / S;              // = max(p)
    float S2 = 0.0f;
#pragma unroll
    for (int o = 0; o < O_; ++o) S2 += expf(expf(acc[o] - m) * inv - inv);
    lossc = (inv + logf(S2) - etgt * inv) * (1.0f / (float)B_);
    corr = (pred == tgt) ? 1.0f : 0.0f;
  }
  if (lane == 0) { sl[widx] = lossc; sc[widx] = corr; }
  __syncthreads();
  if (threadIdx.x == 0) {
    partials[blockIdx.x]       = sl[0] + sl[1] + sl[2] + sl[3];
    partials[NB_ + blockIdx.x] = sc[0] + sc[1] + sc[2] + sc[3];
  }
}

__global__ __launch_bounds__(256) void loss_final(
    const float* __restrict__ partials, float* __restrict__ out, float samples)
{
  float a = 0.0f, c = 0.0f;
  for (int i = threadIdx.x; i < NB_; i += 256) { a += partials[i]; c += partials[NB_ + i]; }
  __shared__ float sl[256], sc[256];
  sl[threadIdx.x] = a; sc[threadIdx.x] = c;
  __syncthreads();
  for (int s = 128; s > 0; s >>= 1) {
    if (threadIdx.x < s) {
      sl[threadIdx.x] += sl[threadIdx.x + s];
      sc[threadIdx.x] += sc[threadIdx.x + s];
    }
    __syncthreads();
  }
  if (threadIdx.x == 0) {
    out[0] = sl[0];
    out[1 + (size_t)M_ * O_] = sc[0];
    out[2 + (size_t)M_ * O_] = samples;
  }
}

extern "C" void kernel_launch(void* const* d_in, const int* in_sizes, int n_in,
                              void* d_out, int out_size, void* d_ws, size_t ws_size,
                              hipStream_t stream) {
  const float* input  = (const float*)d_in[0];
  const int*   target = (const int*)d_in[1];
  const float* v_init = (const float*)d_in[2];
  const float* W1     = (const float*)d_in[3];
  const float* W2     = (const float*)d_in[4];
  const float* tau_n  = (const float*)d_in[5];
  const float* tau_m  = (const float*)d_in[6];
  const float* Wout   = (const float*)d_in[7];
  const float* bout   = (const float*)d_in[8];
  float* out = (float*)d_out;
  float* oh  = out + 1;

  // ws layout: Wb[2*512*352 bf16] spikes[500*100*512 u8] partials[2*NB_ f32]
  unsigned short* Wb = (unsigned short*)d_ws;
  unsigned char* spikes = (unsigned char*)(Wb + (size_t)2 * H_ * KP_);
  float* partials = (float*)(spikes + (size_t)B_ * T_ * H_);

  hipLaunchKernelGGL(convert_w, dim3((2 * H_ * KP_ / 8) / 256), dim3(256), 0, stream,
                     W1, W2, Wb);

  hipLaunchKernelGGL(fused_drive_scan, dim3(B_), dim3(1024), 0, stream,
                     input, Wb, v_init, tau_n, tau_m, spikes);

  hipLaunchKernelGGL(out_loss, dim3(NB_), dim3(256), 0, stream,
                     spikes, Wout, bout, target, oh, partials);

  int mcount = 0;
  for (int t = 0; t < T_; ++t)
    if (t > START_T && ((t - START_T) % (CODING_T + REMAIN_T)) > REMAIN_T) mcount++;
  hipLaunchKernelGGL(loss_final, dim3(1), dim3(256), 0, stream, partials,
                     out, (float)(mcount * B_));
}